// Round 3
// baseline (205.772 us; speedup 1.0000x reference)
//
#include <hip/hip_runtime.h>
#include <hip/hip_bf16.h>
#include <math.h>

#define D_DIM 1024
#define NROWS 32768      // 4*16*512
#define NE_ROWS 1024     // 4*16*16 unique engram rows
#define A1_ROWS 1536     // engram rows + 512 pos rows
#define NT 32            // K tiles of 32

typedef __attribute__((ext_vector_type(8))) short bf16x8;
typedef __attribute__((ext_vector_type(4))) float f32x4;

static __device__ __forceinline__ ushort f2bf(float f) {
  union { float f; unsigned u; } un; un.f = f;
  unsigned u = un.u;
  unsigned r = u + 0x7fffu + ((u >> 16) & 1u);
  return (ushort)(r >> 16);
}

static __device__ __forceinline__ float gelu_exact(float v) {
  return 0.5f * v * (1.0f + erff(v * 0.70710678118654752f));
}

// ---- cast fp32 -> bf16, vectorized x4 ----
__global__ void cast_kernel(const float* __restrict__ src, ushort* __restrict__ dst, int n4) {
  int i = blockIdx.x * blockDim.x + threadIdx.x;
  if (i >= n4) return;
  float4 v = ((const float4*)src)[i];
  ushort4 o;
  o.x = f2bf(v.x); o.y = f2bf(v.y); o.z = f2bf(v.z); o.w = f2bf(v.w);
  ((ushort4*)dst)[i] = o;
}

// ---- 128x128 bf16 MFMA GEMM (m97 structure + row^slot swizzle) — GEMM1 ----
__global__ __launch_bounds__(256) void gemm_bt(const ushort* __restrict__ A,
                                               const ushort* __restrict__ B,
                                               float* __restrict__ C,
                                               int M, int N, int K) {
  __shared__ ushort sA[128 * 64];
  __shared__ ushort sB[128 * 64];

  int nwg = gridDim.x;
  int bid = blockIdx.x;
  if ((nwg & 7) == 0) {
    int cpx = nwg >> 3;
    bid = (bid & 7) * cpx + (bid >> 3);
  }
  int ntn = N >> 7;
  int mt = bid / ntn, nt = bid % ntn;
  int brow = mt << 7, bcol = nt << 7;

  int tid = threadIdx.x;
  int wv = tid >> 6, lane = tid & 63;
  int wm = (wv >> 1) << 6, wn = (wv & 1) << 6;
  int lr = lane & 15, lk = lane >> 4;
  int srow = lane >> 3;
  // T2: phys 16B-slot p at row r holds logical slot p^(r&7); linear LDS dest,
  // pre-swizzled global source (row&7 == (lane>>3)&7 for this staging map)
  int scolsw = (((lane & 7) ^ ((lane >> 3) & 7)) << 3);

  f32x4 acc[4][4];
#pragma unroll
  for (int m = 0; m < 4; ++m)
#pragma unroll
    for (int n = 0; n < 4; ++n) acc[m][n] = (f32x4){0.f, 0.f, 0.f, 0.f};

  for (int k0 = 0; k0 < K; k0 += 64) {
    __syncthreads();
#pragma unroll
    for (int j = 0; j < 4; ++j) {
      int c = (wv << 2) + j;
      int row = (c << 3) + srow;
      const ushort* gA = A + (brow + row) * K + k0 + scolsw;
      const ushort* gB = B + (bcol + row) * K + k0 + scolsw;
      __builtin_amdgcn_global_load_lds(
          (const __attribute__((address_space(1))) unsigned int*)gA,
          (__attribute__((address_space(3))) unsigned int*)&sA[c << 9], 16, 0, 0);
      __builtin_amdgcn_global_load_lds(
          (const __attribute__((address_space(1))) unsigned int*)gB,
          (__attribute__((address_space(3))) unsigned int*)&sB[c << 9], 16, 0, 0);
    }
    __syncthreads();
#pragma unroll
    for (int kk = 0; kk < 2; ++kk) {
      int rdoff = (((kk << 2) | lk) ^ (lr & 7)) << 3;   // swizzled read slot
      bf16x8 af[4], bfr[4];
#pragma unroll
      for (int m = 0; m < 4; ++m)
        af[m] = *(const bf16x8*)&sA[(wm + (m << 4) + lr) * 64 + rdoff];
#pragma unroll
      for (int n = 0; n < 4; ++n)
        bfr[n] = *(const bf16x8*)&sB[(wn + (n << 4) + lr) * 64 + rdoff];
#pragma unroll
      for (int m = 0; m < 4; ++m)
#pragma unroll
        for (int n = 0; n < 4; ++n)
          acc[m][n] = __builtin_amdgcn_mfma_f32_16x16x32_bf16(af[m], bfr[n], acc[m][n], 0, 0, 0);
    }
  }

#pragma unroll
  for (int m = 0; m < 4; ++m)
#pragma unroll
    for (int n = 0; n < 4; ++n)
#pragma unroll
      for (int i = 0; i < 4; ++i) {
        int row = brow + wm + (m << 4) + (lk << 2) + i;
        int col = bcol + wn + (n << 4) + lr;
        C[(long)row * N + col] = acc[m][n][i];
      }
}

// ---- fused GEMM2 + gelu-staging + LayerNorm ----
// out = LN( (eng+pos) + gelu(xw1_e + xw1_p + b1) @ W2^T + b2 )
// BM=64, BN=1024 (full row), BK=32, 8 waves, wave-tile 64x128 (cols wv*64 and 512+wv*64).
__global__ __launch_bounds__(512, 2) void gemm2_ln(
    const float* __restrict__ xw1,    // [1536][1024] f32: rows 0-1023 e@W1T, 1024-1535 p@W1T
    const ushort* __restrict__ W2b,   // [1024][1024] bf16
    const float* __restrict__ b1,
    const float* __restrict__ eng, const float* __restrict__ pos,
    const float* __restrict__ b2, const float* __restrict__ gamma_,
    const float* __restrict__ beta_, float* __restrict__ out) {
  __shared__ ushort sB0[2][16384];   // B rows 0-511,  [buf][512r x 32k]  64 KiB
  __shared__ ushort sB1[2][16384];   // B rows 512-1023                   64 KiB
  __shared__ ushort sAs[2][2048];    // A 64r x 32k                        8 KiB
  __shared__ float red[64][8][2];    // per-row per-wave (sum, sumsq)
  __shared__ float musd[64][2];

  int bid = blockIdx.x;
  bid = (bid & 7) * 64 + (bid >> 3);          // XCD swizzle, 512 blocks
  long brow = (long)bid << 6;
  int w0 = (int)(brow & 511);
  int bn = (int)(brow >> 9);
  int er0 = bn * 16 + (w0 >> 5);

  int tid = threadIdx.x;
  int wv = tid >> 6, lane = tid & 63;
  int lr = lane & 15, lk = lane >> 4;

  // --- B staging: phys slot p at row r holds logical p^((r>>1)&3) ---
  int bRow = tid >> 2;
  int bSlot = (((tid & 3) ^ ((tid >> 3) & 3)) << 3);
  int dOff = wv << 9;                          // ushort units, wave-uniform dest

  // --- A staging (reg->gelu->ds_write) ---
  int aRow = tid >> 3, aQ = tid & 7;
  const float* aEP = xw1 + ((size_t)(er0 + (aRow >> 5)) << 10) + (aQ << 2);
  const float* aPP = xw1 + ((size_t)(NE_ROWS + w0 + aRow) << 10) + (aQ << 2);
  const float* b1P = b1 + (aQ << 2);
  int aWr = aRow * 32 + ((((aQ >> 1) ^ ((aRow >> 1) & 3)) << 3)) + ((aQ & 1) << 2);

  // --- fragment read offsets (swizzled) ---
  int rdswz = (lk ^ ((lr >> 1) & 3)) << 3;
  int aRd = lr * 32 + rdswz;
  int bRd = (wv << 11) + lr * 32 + rdswz;      // wv*64 rows

  f32x4 acc[4][2][4];
#pragma unroll
  for (int m = 0; m < 4; ++m)
#pragma unroll
    for (int h = 0; h < 2; ++h)
#pragma unroll
      for (int f = 0; f < 4; ++f) acc[m][h][f] = (f32x4){0.f, 0.f, 0.f, 0.f};

#define STAGE_B(arr, hofs, buf_, k0_) do {                                        \
    _Pragma("unroll")                                                             \
    for (int j = 0; j < 4; ++j) {                                                 \
      __builtin_amdgcn_global_load_lds(                                           \
        (const __attribute__((address_space(1))) unsigned int*)                   \
          (W2b + ((size_t)((hofs) + j * 128 + bRow) << 10) + (k0_) + bSlot),      \
        (__attribute__((address_space(3))) unsigned int*)&arr[buf_][(j << 12) + dOff], \
        16, 0, 0);                                                                \
    } } while (0)

  // ---- prologue: tile 0 ----
  {
    float4 ae = *(const float4*)aEP;
    float4 ap = *(const float4*)aPP;
    float4 ab = *(const float4*)b1P;
    STAGE_B(sB0, 0, 0, 0);
    STAGE_B(sB1, 512, 0, 0);
    asm volatile("s_waitcnt vmcnt(0)" ::: "memory");
    ushort4 o;
    o.x = f2bf(gelu_exact(ae.x + ap.x + ab.x));
    o.y = f2bf(gelu_exact(ae.y + ap.y + ab.y));
    o.z = f2bf(gelu_exact(ae.z + ap.z + ab.z));
    o.w = f2bf(gelu_exact(ae.w + ap.w + ab.w));
    *(ushort4*)&sAs[0][aWr] = o;
    asm volatile("s_waitcnt lgkmcnt(0)" ::: "memory");
    __builtin_amdgcn_s_barrier();
  }

  // ---- main loop ----
  for (int t = 0; t < NT - 1; ++t) {
    const int cur = t & 1, nxt = cur ^ 1;
    const int k1 = (t + 1) << 5;
    // ph0: issue next A-loads + next B-half0; compute h0 from current
    float4 ae = *(const float4*)(aEP + k1);
    float4 ap = *(const float4*)(aPP + k1);
    float4 ab = *(const float4*)(b1P + k1);
    STAGE_B(sB0, 0, nxt, k1);
    bf16x8 aF[4], bF[4];
#pragma unroll
    for (int m = 0; m < 4; ++m) aF[m] = *(const bf16x8*)&sAs[cur][aRd + m * 512];
#pragma unroll
    for (int f = 0; f < 4; ++f) bF[f] = *(const bf16x8*)&sB0[cur][bRd + f * 512];
    __builtin_amdgcn_s_setprio(1);
#pragma unroll
    for (int m = 0; m < 4; ++m)
#pragma unroll
      for (int f = 0; f < 4; ++f)
        acc[m][0][f] = __builtin_amdgcn_mfma_f32_16x16x32_bf16(aF[m], bF[f], acc[m][0][f], 0, 0, 0);
    __builtin_amdgcn_s_setprio(0);
    // ph1: certify loads, write gelu'd A(next), barrier, stage B-half1(next), compute h1
    asm volatile("s_waitcnt vmcnt(0)" ::: "memory");
    ushort4 o;
    o.x = f2bf(gelu_exact(ae.x + ap.x + ab.x));
    o.y = f2bf(gelu_exact(ae.y + ap.y + ab.y));
    o.z = f2bf(gelu_exact(ae.z + ap.z + ab.z));
    o.w = f2bf(gelu_exact(ae.w + ap.w + ab.w));
    *(ushort4*)&sAs[nxt][aWr] = o;
    asm volatile("s_waitcnt lgkmcnt(0)" ::: "memory");
    __builtin_amdgcn_s_barrier();
    STAGE_B(sB1, 512, nxt, k1);
#pragma unroll
    for (int f = 0; f < 4; ++f) bF[f] = *(const bf16x8*)&sB1[cur][bRd + f * 512];
    __builtin_amdgcn_s_setprio(1);
#pragma unroll
    for (int m = 0; m < 4; ++m)
#pragma unroll
      for (int f = 0; f < 4; ++f)
        acc[m][1][f] = __builtin_amdgcn_mfma_f32_16x16x32_bf16(aF[m], bF[f], acc[m][1][f], 0, 0, 0);
    __builtin_amdgcn_s_setprio(0);
  }
  // ---- tail tile (NT-1) ----
  {
    const int cur = (NT - 1) & 1;
    bf16x8 aF[4], bF[4];
#pragma unroll
    for (int m = 0; m < 4; ++m) aF[m] = *(const bf16x8*)&sAs[cur][aRd + m * 512];
#pragma unroll
    for (int f = 0; f < 4; ++f) bF[f] = *(const bf16x8*)&sB0[cur][bRd + f * 512];
#pragma unroll
    for (int m = 0; m < 4; ++m)
#pragma unroll
      for (int f = 0; f < 4; ++f)
        acc[m][0][f] = __builtin_amdgcn_mfma_f32_16x16x32_bf16(aF[m], bF[f], acc[m][0][f], 0, 0, 0);
    asm volatile("s_waitcnt vmcnt(0)" ::: "memory");
    __builtin_amdgcn_s_barrier();
#pragma unroll
    for (int f = 0; f < 4; ++f) bF[f] = *(const bf16x8*)&sB1[cur][bRd + f * 512];
#pragma unroll
    for (int m = 0; m < 4; ++m)
#pragma unroll
      for (int f = 0; f < 4; ++f)
        acc[m][1][f] = __builtin_amdgcn_mfma_f32_16x16x32_bf16(aF[m], bF[f], acc[m][1][f], 0, 0, 0);
  }
#undef STAGE_B

  // ---- epilogue: residual + bias, LN stats, normalize, write ----
  float cb2[8], cg[8], cbt[8];
#pragma unroll
  for (int h = 0; h < 2; ++h)
#pragma unroll
    for (int f = 0; f < 4; ++f) {
      int col = h * 512 + (wv << 6) + (f << 4) + lr;
      cb2[h * 4 + f] = b2[col];
      cg[h * 4 + f] = gamma_[col];
      cbt[h * 4 + f] = beta_[col];
    }
#pragma unroll
  for (int m = 0; m < 4; ++m) {
    const float* eRow = eng + ((size_t)(er0 + (m >> 1)) << 10);
#pragma unroll
    for (int i = 0; i < 4; ++i) {
      int rl = (m << 4) + (lk << 2) + i;
      const float* pRow = pos + ((size_t)(w0 + rl) << 10);
      float s = 0.f, q = 0.f;
#pragma unroll
      for (int h = 0; h < 2; ++h)
#pragma unroll
        for (int f = 0; f < 4; ++f) {
          int col = h * 512 + (wv << 6) + (f << 4) + lr;
          float v = acc[m][h][f][i] + eRow[col] + pRow[col] + cb2[h * 4 + f];
          acc[m][h][f][i] = v;
          s += v; q += v * v;
        }
      s += __shfl_xor(s, 1); q += __shfl_xor(q, 1);
      s += __shfl_xor(s, 2); q += __shfl_xor(q, 2);
      s += __shfl_xor(s, 4); q += __shfl_xor(q, 4);
      s += __shfl_xor(s, 8); q += __shfl_xor(q, 8);
      if (lr == 0) { red[rl][wv][0] = s; red[rl][wv][1] = q; }
    }
  }
  __syncthreads();
  if (wv == 0) {
    float S = 0.f, Q = 0.f;
#pragma unroll
    for (int j = 0; j < 8; ++j) { S += red[lane][j][0]; Q += red[lane][j][1]; }
    float mu = S * (1.0f / 1024.0f);
    float var = Q * (1.0f / 1024.0f) - mu * mu;
    musd[lane][0] = mu;
    musd[lane][1] = rsqrtf(var + 1e-5f);
  }
  __syncthreads();
#pragma unroll
  for (int m = 0; m < 4; ++m)
#pragma unroll
    for (int i = 0; i < 4; ++i) {
      int rl = (m << 4) + (lk << 2) + i;
      float mu = musd[rl][0], rs = musd[rl][1];
      float* orow = out + ((brow + rl) << 10);
#pragma unroll
      for (int h = 0; h < 2; ++h)
#pragma unroll
        for (int f = 0; f < 4; ++f) {
          int col = h * 512 + (wv << 6) + (f << 4) + lr;
          orow[col] = (acc[m][h][f][i] - mu) * rs * cg[h * 4 + f] + cbt[h * 4 + f];
        }
    }
}

extern "C" void kernel_launch(void* const* d_in, const int* in_sizes, int n_in,
                              void* d_out, int out_size, void* d_ws, size_t ws_size,
                              hipStream_t stream) {
  const float* eng   = (const float*)d_in[0];
  const float* pos   = (const float*)d_in[1];
  const float* w1    = (const float*)d_in[2];
  const float* b1    = (const float*)d_in[3];
  const float* w2    = (const float*)d_in[4];
  const float* b2    = (const float*)d_in[5];
  const float* gamma = (const float*)d_in[6];
  const float* beta  = (const float*)d_in[7];
  float* out = (float*)d_out;

  char* ws = (char*)d_ws;
  ushort* w1b = (ushort*)(ws);                     // 2 MiB
  ushort* w2b = (ushort*)(ws + (2u << 20));        // 2 MiB
  ushort* a1b = (ushort*)(ws + (4u << 20));        // 3 MiB: 1536x1024 bf16
  float*  xw1 = (float*)(ws + (7u << 20));         // 6 MiB: 1536x1024 f32

  // 1) casts to bf16
  cast_kernel<<<1024, 256, 0, stream>>>(w1, w1b, 1024 * 1024 / 4);
  cast_kernel<<<1024, 256, 0, stream>>>(w2, w2b, 1024 * 1024 / 4);
  cast_kernel<<<1024, 256, 0, stream>>>(eng, a1b, 1024 * 1024 / 4);
  cast_kernel<<<512, 256, 0, stream>>>(pos, a1b + 1024 * 1024, 512 * 1024 / 4);

  // 2) GEMM1: xw1 = [engrams; pos] @ W1^T   (1536 x 1024 x 1024)
  gemm_bt<<<(A1_ROWS / 128) * (D_DIM / 128), 256, 0, stream>>>(a1b, w1b, xw1,
                                                               A1_ROWS, D_DIM, D_DIM);

  // 3) fused GEMM2 + gelu staging + residual + LayerNorm -> d_out
  gemm2_ln<<<NROWS / 64, 512, 0, stream>>>(xw1, w2b, b1, eng, pos, b2, gamma, beta, out);
}

// Round 4
// 173.053 us; speedup vs baseline: 1.1891x; 1.1891x over previous
//
#include <hip/hip_runtime.h>
#include <hip/hip_bf16.h>
#include <math.h>

#define D_DIM 1024
#define NROWS 32768      // 4*16*512
#define NE_ROWS 1024     // 4*16*16 unique engram rows
#define A1_ROWS 1536     // engram rows + 512 pos rows
#define NT2 16           // GEMM2 K-tiles of 64

typedef __attribute__((ext_vector_type(8))) short bf16x8;
typedef __attribute__((ext_vector_type(4))) float f32x4;

static __device__ __forceinline__ ushort f2bf(float f) {
  union { float f; unsigned u; } un; un.f = f;
  unsigned u = un.u;
  unsigned r = u + 0x7fffu + ((u >> 16) & 1u);
  return (ushort)(r >> 16);
}
static __device__ __forceinline__ float bf2f(ushort h) {
  union { unsigned u; float f; } un; un.u = ((unsigned)h) << 16;
  return un.f;
}
static __device__ __forceinline__ float gelu_exact(float v) {
  return 0.5f * v * (1.0f + erff(v * 0.70710678118654752f));
}

// ---- fused cast fp32 -> bf16 of w1|w2|eng|pos into contiguous ws region ----
__global__ void cast_all_kernel(const float* __restrict__ w1, const float* __restrict__ w2,
                                const float* __restrict__ eng, const float* __restrict__ pos,
                                ushort* __restrict__ dst) {
  int i = blockIdx.x * blockDim.x + threadIdx.x;   // float4 units, 0..917503
  float4 v;
  if (i < 262144) v = ((const float4*)w1)[i];
  else if (i < 524288) v = ((const float4*)w2)[i - 262144];
  else if (i < 786432) v = ((const float4*)eng)[i - 524288];
  else v = ((const float4*)pos)[i - 786432];
  ushort4 o;
  o.x = f2bf(v.x); o.y = f2bf(v.y); o.z = f2bf(v.z); o.w = f2bf(v.w);
  ((ushort4*)dst)[i] = o;
}

// ---- 128x128 bf16 MFMA GEMM (m97 structure + swizzle) — small GEMM1 ----
__global__ __launch_bounds__(256) void gemm_bt(const ushort* __restrict__ A,
                                               const ushort* __restrict__ B,
                                               float* __restrict__ C,
                                               int M, int N, int K) {
  __shared__ ushort sA[128 * 64];
  __shared__ ushort sB[128 * 64];

  int nwg = gridDim.x;
  int bid = blockIdx.x;
  if ((nwg & 7) == 0) {
    int cpx = nwg >> 3;
    bid = (bid & 7) * cpx + (bid >> 3);
  }
  int ntn = N >> 7;
  int mt = bid / ntn, nt = bid % ntn;
  int brow = mt << 7, bcol = nt << 7;

  int tid = threadIdx.x;
  int wv = tid >> 6, lane = tid & 63;
  int wm = (wv >> 1) << 6, wn = (wv & 1) << 6;
  int lr = lane & 15, lk = lane >> 4;
  int srow = lane >> 3;
  int scolsw = (((lane & 7) ^ ((lane >> 3) & 7)) << 3);

  f32x4 acc[4][4];
#pragma unroll
  for (int m = 0; m < 4; ++m)
#pragma unroll
    for (int n = 0; n < 4; ++n) acc[m][n] = (f32x4){0.f, 0.f, 0.f, 0.f};

  for (int k0 = 0; k0 < K; k0 += 64) {
    __syncthreads();
#pragma unroll
    for (int j = 0; j < 4; ++j) {
      int c = (wv << 2) + j;
      int row = (c << 3) + srow;
      const ushort* gA = A + (brow + row) * K + k0 + scolsw;
      const ushort* gB = B + (bcol + row) * K + k0 + scolsw;
      __builtin_amdgcn_global_load_lds(
          (const __attribute__((address_space(1))) unsigned int*)gA,
          (__attribute__((address_space(3))) unsigned int*)&sA[c << 9], 16, 0, 0);
      __builtin_amdgcn_global_load_lds(
          (const __attribute__((address_space(1))) unsigned int*)gB,
          (__attribute__((address_space(3))) unsigned int*)&sB[c << 9], 16, 0, 0);
    }
    __syncthreads();
#pragma unroll
    for (int kk = 0; kk < 2; ++kk) {
      int rdoff = (((kk << 2) | lk) ^ (lr & 7)) << 3;
      bf16x8 af[4], bfr[4];
#pragma unroll
      for (int m = 0; m < 4; ++m)
        af[m] = *(const bf16x8*)&sA[(wm + (m << 4) + lr) * 64 + rdoff];
#pragma unroll
      for (int n = 0; n < 4; ++n)
        bfr[n] = *(const bf16x8*)&sB[(wn + (n << 4) + lr) * 64 + rdoff];
#pragma unroll
      for (int m = 0; m < 4; ++m)
#pragma unroll
        for (int n = 0; n < 4; ++n)
          acc[m][n] = __builtin_amdgcn_mfma_f32_16x16x32_bf16(af[m], bfr[n], acc[m][n], 0, 0, 0);
    }
  }

#pragma unroll
  for (int m = 0; m < 4; ++m)
#pragma unroll
    for (int n = 0; n < 4; ++n)
#pragma unroll
      for (int i = 0; i < 4; ++i) {
        int row = brow + wm + (m << 4) + (lk << 2) + i;
        int col = bcol + wn + (n << 4) + lr;
        C[(long)row * N + col] = acc[m][n][i];
      }
}

// ---- h = gelu_exact(xw1_e[er] + xw1_p[w] + b1) -> bf16 ----
__global__ __launch_bounds__(256) void gelu_kernel(const float* __restrict__ xw1,
                                                   const float* __restrict__ b1,
                                                   ushort* __restrict__ h) {
  int r = blockIdx.x;
  int t = threadIdx.x;
  int bn = r >> 9;
  int w = r & 511;
  int er = bn * 16 + (w >> 5);
  float4 e = ((const float4*)(xw1 + er * D_DIM))[t];
  float4 p = ((const float4*)(xw1 + (NE_ROWS + w) * D_DIM))[t];
  float4 b = ((const float4*)b1)[t];
  ushort4 o;
  o.x = f2bf(gelu_exact(e.x + p.x + b.x));
  o.y = f2bf(gelu_exact(e.y + p.y + b.y));
  o.z = f2bf(gelu_exact(e.z + p.z + b.z));
  o.w = f2bf(gelu_exact(e.w + p.w + b.w));
  ((ushort4*)(h + (long)r * D_DIM))[t] = o;
}

// ---- GEMM2: 8-phase 256x256 bf16 pipelined (m201 template port) ----
// Y(bf16) = h @ W2^T, Y stored interleaved: ushort at ((ushort*)out) + row*2048 + col.
// BK=64 split in 2 kk-halves; LDS [parity][kkh][256r x 32k] for A and B = 128 KiB.
// Swizzle: phys 16B-slot s at row r holds logical s^((r>>1)&3).
__global__ __launch_bounds__(512, 2) void gemm2_8ph(const ushort* __restrict__ A,
                                                    const ushort* __restrict__ B,
                                                    ushort* __restrict__ Y) {
  __shared__ ushort sA[2][2][8192];
  __shared__ ushort sB[2][2][8192];
  const int K = 1024;

  int bid = blockIdx.x;
  bid = (bid & 7) * 64 + (bid >> 3);          // 512 blocks, XCD swizzle
  int mt = bid >> 2, nt = bid & 3;            // 128 M-tiles x 4 N-tiles
  long brow = (long)mt << 8;
  int bcol = nt << 8;

  int tid = threadIdx.x;
  int wv = tid >> 6, l = tid & 63;
  int wr = wv >> 2, wc = wv & 3;              // 2x4 wave grid; wave tile 128x64
  int lr = l & 15, lk = l >> 4;

  // staging source (per-thread, pre-swizzled global k-slot)
  int sr = (wv << 4) + (l >> 2);              // region row for j=0 (0..127)
  int slog = ((l & 3) ^ ((l >> 3) & 3)) << 3; // logical slot for phys (l&3)
  const ushort* aS = A + (brow + sr) * (long)K + slog;
  const ushort* bS = B + (size_t)(bcol + sr) * K + slog;

  // fragment read offsets (swizzled)
  int rdswz = (lk ^ ((lr >> 1) & 3)) << 3;
  int aO = (((wr << 7) + lr) << 5) + rdswz;   // + m*512
  int bO = (((wc << 6) + lr) << 5) + rdswz;   // + n*512

  f32x4 acc[8][4];
#pragma unroll
  for (int m = 0; m < 8; ++m)
#pragma unroll
    for (int n = 0; n < 4; ++n) acc[m][n] = (f32x4){0.f, 0.f, 0.f, 0.f};

#define STG(SS, SRC, kt, kkh) do {                                                   \
    int p_ = (kt) & 1; int o_ = ((kt) << 6) + ((kkh) << 5);                          \
    __builtin_amdgcn_global_load_lds(                                                \
      (const __attribute__((address_space(1))) unsigned int*)((SRC) + o_),           \
      (__attribute__((address_space(3))) unsigned int*)&SS[p_][kkh][wv << 9], 16, 0, 0); \
    __builtin_amdgcn_global_load_lds(                                                \
      (const __attribute__((address_space(1))) unsigned int*)((SRC) + o_ + 131072),  \
      (__attribute__((address_space(3))) unsigned int*)&SS[p_][kkh][(wv << 9) + 4096], 16, 0, 0); \
  } while (0)

#define BAR asm volatile("s_barrier" ::: "memory")
#define MFMA16(MOFS, BF)                                                             \
    __builtin_amdgcn_s_setprio(1);                                                   \
    _Pragma("unroll")                                                                \
    for (int m = 0; m < 4; ++m)                                                      \
      _Pragma("unroll")                                                              \
      for (int n = 0; n < 4; ++n)                                                    \
        acc[m + MOFS][n] = __builtin_amdgcn_mfma_f32_16x16x32_bf16(af[m], BF[n], acc[m + MOFS][n], 0, 0, 0); \
    __builtin_amdgcn_s_setprio(0)

  // prologue: tile 0 fully staged, drained
  STG(sA, aS, 0, 0); STG(sB, bS, 0, 0); STG(sA, aS, 0, 1); STG(sB, bS, 0, 1);
  asm volatile("s_waitcnt vmcnt(0)" ::: "memory");
  BAR;

  for (int t = 0; t < NT2; ++t) {
    int p = t & 1;
    bf16x8 af[4], bf[4];
    // ph1: (mh0, kk0)
#pragma unroll
    for (int n = 0; n < 4; ++n) bf[n] = *(const bf16x8*)&sB[p][0][bO + (n << 9)];
#pragma unroll
    for (int m = 0; m < 4; ++m) af[m] = *(const bf16x8*)&sA[p][0][aO + (m << 9)];
    if (t + 1 < NT2) STG(sA, aS, t + 1, 0);
    BAR;
    MFMA16(0, bf);
    BAR;
    // ph2: (mh1, kk0)
#pragma unroll
    for (int m = 0; m < 4; ++m) af[m] = *(const bf16x8*)&sA[p][0][aO + ((m + 4) << 9)];
    if (t + 1 < NT2) STG(sB, bS, t + 1, 0);
    BAR;
    MFMA16(4, bf);
    if (t == NT2 - 1) asm volatile("s_waitcnt vmcnt(0)" ::: "memory");
    else              asm volatile("s_waitcnt vmcnt(4)" ::: "memory");
    BAR;
    // ph3: (mh0, kk1)
#pragma unroll
    for (int n = 0; n < 4; ++n) bf[n] = *(const bf16x8*)&sB[p][1][bO + (n << 9)];
#pragma unroll
    for (int m = 0; m < 4; ++m) af[m] = *(const bf16x8*)&sA[p][1][aO + (m << 9)];
    if (t + 1 < NT2) STG(sA, aS, t + 1, 1);
    BAR;
    MFMA16(0, bf);
    BAR;
    // ph4: (mh1, kk1)
#pragma unroll
    for (int m = 0; m < 4; ++m) af[m] = *(const bf16x8*)&sA[p][1][aO + ((m + 4) << 9)];
    if (t + 1 < NT2) STG(sB, bS, t + 1, 1);
    BAR;
    MFMA16(4, bf);
    if (t < NT2 - 1) asm volatile("s_waitcnt vmcnt(4)" ::: "memory");
    BAR;
  }
#undef STG
#undef BAR
#undef MFMA16

  // epilogue: bf16 y into interleaved out rows (first 1024 ushorts of each 4KB row)
#pragma unroll
  for (int m = 0; m < 8; ++m)
#pragma unroll
    for (int n = 0; n < 4; ++n) {
      int col = bcol + (wc << 6) + (n << 4) + lr;
#pragma unroll
      for (int i = 0; i < 4; ++i) {
        long row = brow + (wr << 7) + (m << 4) + (lk << 2) + i;
        Y[(row << 11) + col] = f2bf(acc[m][n][i]);
      }
    }
}

// ---- out = LayerNorm((eng+pos) + y + b2); y read bf16-interleaved from out ----
__global__ __launch_bounds__(256) void ln_kernel(const float* __restrict__ eng,
                                                 const float* __restrict__ pos,
                                                 const float* __restrict__ b2,
                                                 const float* __restrict__ gamma,
                                                 const float* __restrict__ beta,
                                                 float* __restrict__ out) {
  __shared__ float red[8];
  int r = blockIdx.x;
  int t = threadIdx.x;
  int bn = r >> 9, w = r & 511;
  int er = bn * 16 + (w >> 5);
  float4 xe = ((const float4*)(eng + er * D_DIM))[t];
  float4 xp = ((const float4*)(pos + w * D_DIM))[t];
  ushort4 yv = ((const ushort4*)((const ushort*)out + ((size_t)r << 11)))[t];
  float4 bb = ((const float4*)b2)[t];
  float v0 = xe.x + xp.x + bf2f(yv.x) + bb.x;
  float v1 = xe.y + xp.y + bf2f(yv.y) + bb.y;
  float v2 = xe.z + xp.z + bf2f(yv.z) + bb.z;
  float v3 = xe.w + xp.w + bf2f(yv.w) + bb.w;
  float s  = v0 + v1 + v2 + v3;
  float sq = v0 * v0 + v1 * v1 + v2 * v2 + v3 * v3;
  int lane = t & 63, wv = t >> 6;
#pragma unroll
  for (int off = 32; off > 0; off >>= 1) {
    s  += __shfl_down(s, off);
    sq += __shfl_down(sq, off);
  }
  if (lane == 0) { red[wv] = s; red[4 + wv] = sq; }
  __syncthreads();
  float S  = red[0] + red[1] + red[2] + red[3];
  float SQ = red[4] + red[5] + red[6] + red[7];
  float mu = S * (1.0f / 1024.0f);
  float var = SQ * (1.0f / 1024.0f) - mu * mu;
  float rs = rsqrtf(var + 1e-5f);
  float4 g = ((const float4*)gamma)[t];
  float4 bt = ((const float4*)beta)[t];
  float4 o;
  o.x = (v0 - mu) * rs * g.x + bt.x;
  o.y = (v1 - mu) * rs * g.y + bt.y;
  o.z = (v2 - mu) * rs * g.z + bt.z;
  o.w = (v3 - mu) * rs * g.w + bt.w;
  ((float4*)(out + ((size_t)r << 10)))[t] = o;
}

extern "C" void kernel_launch(void* const* d_in, const int* in_sizes, int n_in,
                              void* d_out, int out_size, void* d_ws, size_t ws_size,
                              hipStream_t stream) {
  const float* eng   = (const float*)d_in[0];
  const float* pos   = (const float*)d_in[1];
  const float* w1    = (const float*)d_in[2];
  const float* b1    = (const float*)d_in[3];
  const float* w2    = (const float*)d_in[4];
  const float* b2    = (const float*)d_in[5];
  const float* gamma = (const float*)d_in[6];
  const float* beta  = (const float*)d_in[7];
  float* out = (float*)d_out;

  char* ws = (char*)d_ws;
  ushort* w1b = (ushort*)(ws);                     // 2 MiB  (cast block start)
  ushort* w2b = (ushort*)(ws + (2u << 20));        // 2 MiB
  ushort* a1b = (ushort*)(ws + (4u << 20));        // 3 MiB: [eng;pos] bf16
  float*  xw1 = (float*)(ws + (7u << 20));         // 6 MiB: 1536x1024 f32
  ushort* hb  = (ushort*)(ws + (13u << 20));       // 64 MiB: 32768x1024 bf16

  // 1) fused casts to bf16 (w1|w2|eng|pos contiguous at ws base)
  cast_all_kernel<<<3584, 256, 0, stream>>>(w1, w2, eng, pos, w1b);

  // 2) GEMM1: xw1 = [engrams; pos] @ W1^T   (1536 x 1024 x 1024)
  gemm_bt<<<(A1_ROWS / 128) * (D_DIM / 128), 256, 0, stream>>>(a1b, w1b, xw1,
                                                               A1_ROWS, D_DIM, D_DIM);

  // 3) h = gelu(xw1_e + xw1_p + b1) -> bf16
  gelu_kernel<<<NROWS, 256, 0, stream>>>(xw1, b1, hb);

  // 4) GEMM2 (8-phase): y(bf16) = h @ W2^T, interleaved into d_out rows
  gemm2_8ph<<<512, 512, 0, stream>>>(hb, w2b, (ushort*)out);

  // 5) LayerNorm epilogue (exact fp32 residual recompute)
  ln_kernel<<<NROWS, 256, 0, stream>>>(eng, pos, b2, gamma, beta, out);
}